// Round 7
// baseline (307.940 us; speedup 1.0000x reference)
//
#include <hip/hip_runtime.h>

#define N_P 1024
#define N_K 16
#define C_IN 18

typedef _Float16 f16;
typedef f16 f16x8 __attribute__((ext_vector_type(8)));
typedef f16 f16x4 __attribute__((ext_vector_type(4)));
typedef float f32x4 __attribute__((ext_vector_type(4)));

// ---------------------------------------------------------------------------
// Fused EdgeConv. Round-7: same-wave segments + shfl tree-merge (no part LDS).
//  - thread: query qid = lane&15 (wave-local), segment s = lane>>4.
//    Each thread scans its 256-candidate segment with the f64-key cascade
//    (key = (mono(d)<<10)|idx exact in f64; order == reference (d,idx) lex).
//  - segment reads bank-skewed (start offset 2s) so the 4 broadcast addrs
//    per wave hit distinct bank groups.
//  - merge: 2 rounds of __shfl_xor (32 then 16), snapshot 17 keys, cascade-
//    insert. Lanes 0-15 end with final top-17; kk[0] = self, dropped.
//  - MLP phase unchanged (verified absmax 0.0625 since round 3).
// LDS: spts[1024]f4 (16384) aliased by fbuf[64][65] (16640), hb 9216,
//      idx_lds 4096, msum -> 29968 B total => up to 5 blocks/CU.
// ---------------------------------------------------------------------------
__global__ __launch_bounds__(256, 4) void fused_kernel(
    const float* __restrict__ feat, const unsigned char* __restrict__ mask,
    const float* __restrict__ W0, const float* __restrict__ W1,
    const float* __restrict__ W2, const float* __restrict__ Ws,
    const float* __restrict__ g0, const float* __restrict__ b0,
    const float* __restrict__ m0, const float* __restrict__ v0,
    const float* __restrict__ g1, const float* __restrict__ b1,
    const float* __restrict__ m1, const float* __restrict__ v1,
    const float* __restrict__ g2, const float* __restrict__ b2,
    const float* __restrict__ m2, const float* __restrict__ v2,
    const float* __restrict__ gs, const float* __restrict__ bs,
    const float* __restrict__ ms, const float* __restrict__ vs,
    float* __restrict__ out) {

    __shared__ __align__(16) char sbytes[16640 + 9216 + 4096 + 16];
    float4* spts = (float4*)sbytes;                          // [1024]
    float (*fbuf)[65] = (float(*)[65])sbytes;                // aliases spts
    f16 (*hb)[16][72] = (f16(*)[16][72])(sbytes + 16640);    // [4][16][72]
    int (*idx_lds)[16] = (int(*)[16])(sbytes + 16640 + 9216);// [64][16]
    int* msum = (int*)(sbytes + 16640 + 9216 + 4096);

    const int tid = threadIdx.x;
    const int lane = tid & 63;
    const int w = tid >> 6;
    const int g = lane >> 4;
    const int c15 = lane & 15;
    const int n = blockIdx.x >> 4;
    const int P0 = (blockIdx.x & 15) << 6;   // this block's 64 points
    const int PB = P0 + (w << 4);            // this wave's 16 points

    const float* fB = feat + (size_t)n * N_P * C_IN;

    // ---- phase A: stage (x, y, r); count mask ----
    if (tid == 0) *msum = 0;
    __syncthreads();
    for (int i = tid; i < N_P; i += 256) {
        float x = fB[i * C_IN + 0];
        float y = fB[i * C_IN + 1];
        float r = __fadd_rn(__fmul_rn(x, x), __fmul_rn(y, y));
        spts[i] = make_float4(x, y, r, 0.f);
    }
    {
        unsigned int m4 = *(const unsigned int*)(mask + (size_t)n * N_P + tid * 4);
        int mc = (int)(((m4 & 0xFFu) != 0) + (((m4 >> 8) & 0xFFu) != 0) +
                       (((m4 >> 16) & 0xFFu) != 0) + (((m4 >> 24) & 0xFFu) != 0));
        atomicAdd(msum, mc);
    }
    __syncthreads();
    const int valid = N_P - *msum;

    // ---- phase B: segmented scan + in-wave shfl merge ----
    double kk[17];
    {
        const int qid = c15;                 // wave-local query 0..15
        const int s = g;                     // segment 0..3
        const int base = s << 8;
        const float4 me = spts[P0 + (w << 4) + qid];
        const float px = me.x, py = me.y, rp = me.z;

#pragma unroll
        for (int j = 0; j < 17; ++j) kk[j] = 0x1.0p60;

        int off = (2 * s) & 255;             // bank-skewed start
        float4 nq = spts[base + off];
        for (int i = 0; i < 256; ++i) {
            const float4 qc = nq;
            const int cur = base + off;
            off = (off + 1) & 255;
            nq = spts[base + off];           // broadcast prefetch
            float dot = __fadd_rn(__fmul_rn(px, qc.x), __fmul_rn(py, qc.y));
            float d   = __fadd_rn(__builtin_fmaf(-2.f, dot, rp), qc.z);
            unsigned int ud = __float_as_uint(d);
            ud ^= (unsigned int)((int)ud >> 31) | 0x80000000u;   // monotone map
            double x = __builtin_fma((double)ud, 1024.0, (double)cur); // exact
            // branchless sorted-ascending cascade
#pragma unroll
            for (int j = 0; j < 17; ++j) {
                double lo = fmin(kk[j], x);
                x = fmax(kk[j], x);
                kk[j] = lo;
            }
        }
        // tree merge: xor 32, then xor 16 (snapshot then insert)
#pragma unroll
        for (int r = 0; r < 2; ++r) {
            const int m = r == 0 ? 32 : 16;
            double tmp[17];
#pragma unroll
            for (int j = 0; j < 17; ++j) tmp[j] = __shfl_xor(kk[j], m, 64);
#pragma unroll
            for (int j = 0; j < 17; ++j) {
                double x = tmp[j];
#pragma unroll
                for (int jj = 0; jj < 17; ++jj) {
                    double lo = fmin(kk[jj], x);
                    x = fmax(kk[jj], x);
                    kk[jj] = lo;
                }
            }
        }
        if (lane < 16) {
            const int row = (w << 4) + qid;
            // kk[0] = lex-min (d,idx) = self, dropped; kk[1..16] = neighbors
#pragma unroll
            for (int j = 1; j < 17; ++j) {
                double hi = __builtin_trunc(kk[j] * 0x1.0p-10);
                idx_lds[row][j - 1] = (int)(kk[j] - hi * 1024.0);
            }
        }
    }
    __syncthreads();   // all scans done; spts dead -> fbuf writable

    // ---- fold BN into weight fragments (per-lane registers) ----
    float tb0[4], tb1[4], tb2[4], tbs[4];
    f16x8 w0f[4], w1f[4][2], w2f[4][2];
    f16x4 wsf[4];
#pragma unroll
    for (int t = 0; t < 4; ++t) {
        const int o = t * 16 + c15;
        float s0 = g0[o] / sqrtf(v0[o] + 1e-5f);  tb0[t] = b0[o] - m0[o] * s0;
        float s1 = g1[o] / sqrtf(v1[o] + 1e-5f);  tb1[t] = b1[o] - m1[o] * s1;
        float s2 = g2[o] / sqrtf(v2[o] + 1e-5f);  tb2[t] = b2[o] - m2[o] * s2;
        float ss = gs[o] / sqrtf(vs[o] + 1e-5f);  tbs[t] = bs[o] - ms[o] * ss;
        const float* w0r = W0 + o * 32 + g * 8;
#pragma unroll
        for (int e = 0; e < 8; ++e) w0f[t][e] = (f16)(w0r[e] * s0);
        const float* w1r = W1 + o * 64 + g * 8;
        const float* w2r = W2 + o * 64 + g * 8;
#pragma unroll
        for (int ch = 0; ch < 2; ++ch)
#pragma unroll
            for (int e = 0; e < 8; ++e) {
                w1f[t][ch][e] = (f16)(w1r[ch * 32 + e] * s1);
                w2f[t][ch][e] = (f16)(w2r[ch * 32 + e] * s2);
            }
        const float* wsr = Ws + o * 16 + g * 4;
#pragma unroll
        for (int e = 0; e < 4; ++e) wsf[t][e] = (f16)(wsr[e] * ss);
    }

    // ---- per-point MLP: rows = 16 neighbors, cols = 64 channels ----
    for (int pp = 0; pp < 16; ++pp) {
        const int p = PB + pp;
        const int* ip = idx_lds[(w << 4) + pp];

        const int q = ip[c15];
        const int half = g & 1;
        const float* fcp = fB + p * C_IN + 2 + half * 8;
        float e0[8];
#pragma unroll
        for (int j = 0; j < 4; ++j) {
            float2 v = *(const float2*)(fcp + 2 * j);
            e0[2 * j] = v.x; e0[2 * j + 1] = v.y;
        }
        if (g >= 2) {
            const float* fqp = fB + q * C_IN + 2 + half * 8;
#pragma unroll
            for (int j = 0; j < 4; ++j) {
                float2 v = *(const float2*)(fqp + 2 * j);
                e0[2 * j] -= v.x; e0[2 * j + 1] -= v.y;
            }
        }
        f16x8 a0;
#pragma unroll
        for (int j = 0; j < 8; ++j) a0[j] = (f16)e0[j];

        // layer 0 (K=32), folded-BN bias in acc init
        f32x4 acc[4];
#pragma unroll
        for (int t = 0; t < 4; ++t) {
            acc[t] = (f32x4){tb0[t], tb0[t], tb0[t], tb0[t]};
            acc[t] = __builtin_amdgcn_mfma_f32_16x16x32_f16(a0, w0f[t], acc[t], 0, 0, 0);
        }
#pragma unroll
        for (int t = 0; t < 4; ++t)
#pragma unroll
            for (int r = 0; r < 4; ++r)
                hb[w][4 * g + r][t * 16 + c15] = (f16)fmaxf(acc[t][r], 0.f);

        // layer 1 (K=64)
        f16x8 a1a = *(const f16x8*)&hb[w][c15][g * 8];
        f16x8 a1b = *(const f16x8*)&hb[w][c15][32 + g * 8];
        f32x4 acc1[4];
#pragma unroll
        for (int t = 0; t < 4; ++t) {
            acc1[t] = (f32x4){tb1[t], tb1[t], tb1[t], tb1[t]};
            acc1[t] = __builtin_amdgcn_mfma_f32_16x16x32_f16(a1a, w1f[t][0], acc1[t], 0, 0, 0);
            acc1[t] = __builtin_amdgcn_mfma_f32_16x16x32_f16(a1b, w1f[t][1], acc1[t], 0, 0, 0);
        }
#pragma unroll
        for (int t = 0; t < 4; ++t)
#pragma unroll
            for (int r = 0; r < 4; ++r)
                hb[w][4 * g + r][t * 16 + c15] = (f16)fmaxf(acc1[t][r], 0.f);

        // layer 2 (K=64) + neighbor mask + k-mean
        f16x8 a2a = *(const f16x8*)&hb[w][c15][g * 8];
        f16x8 a2b = *(const f16x8*)&hb[w][c15][32 + g * 8];
        f32x4 acc2[4];
#pragma unroll
        for (int t = 0; t < 4; ++t) {
            acc2[t] = (f32x4){tb2[t], tb2[t], tb2[t], tb2[t]};
            acc2[t] = __builtin_amdgcn_mfma_f32_16x16x32_f16(a2a, w2f[t][0], acc2[t], 0, 0, 0);
            acc2[t] = __builtin_amdgcn_mfma_f32_16x16x32_f16(a2b, w2f[t][1], acc2[t], 0, 0, 0);
        }
        float ssum[4] = {0.f, 0.f, 0.f, 0.f};
        int cnt = 0;
#pragma unroll
        for (int r = 0; r < 4; ++r) {
            int qq = ip[4 * g + r];
            bool fl = (qq >= valid);
            cnt += fl ? 1 : 0;
#pragma unroll
            for (int t = 0; t < 4; ++t) {
                float v = fmaxf(acc2[t][r], 0.f);
                ssum[t] += fl ? 0.f : v;
            }
        }
#pragma unroll
        for (int t = 0; t < 4; ++t) {
            ssum[t] += __shfl_xor(ssum[t], 16);
            ssum[t] += __shfl_xor(ssum[t], 32);
        }
        cnt += __shfl_xor(cnt, 16);
        cnt += __shfl_xor(cnt, 32);
        float dn = fmaxf((float)(N_K - cnt), 1e-8f);
        if (g == 0) {
            int prow = (w << 4) + pp;
#pragma unroll
            for (int t = 0; t < 4; ++t)
                fbuf[prow][t * 16 + c15] = ssum[t] / dn;
        }
    }

    // ---- shortcut: sc = BN(Ws @ X) via 16x16x16 MFMA, rows = wave's 16 p ----
    {
        const float* xr = fB + (size_t)(PB + c15) * C_IN + 2 + g * 4;
        float2 xa = *(const float2*)(xr);
        float2 xb = *(const float2*)(xr + 2);
        f16x4 as;
        as[0] = (f16)xa.x; as[1] = (f16)xa.y; as[2] = (f16)xb.x; as[3] = (f16)xb.y;
        f32x4 sacc[4];
#pragma unroll
        for (int t = 0; t < 4; ++t) {
            sacc[t] = (f32x4){tbs[t], tbs[t], tbs[t], tbs[t]};
            sacc[t] = __builtin_amdgcn_mfma_f32_16x16x16f16(as, wsf[t], sacc[t], 0, 0, 0);
        }
        const unsigned char* mrow = mask + (size_t)n * N_P + P0;
#pragma unroll
        for (int r = 0; r < 4; ++r) {
            int pl = (w << 4) + 4 * g + r;
            bool mk = (mrow[pl] != 0);
#pragma unroll
            for (int t = 0; t < 4; ++t) {
                float a = fbuf[pl][t * 16 + c15];
                float sv = mk ? 0.f : sacc[t][r];
                fbuf[pl][t * 16 + c15] = fmaxf(a + sv, 0.f);
            }
        }
    }
    __syncthreads();

    // ---- transposed store: out[n][o][p], coalesced 256B per wave ----
    float* ob = out + (size_t)n * 64 * N_P + P0;
#pragma unroll
    for (int oo = 0; oo < 16; ++oo) {
        int o = (w << 4) + oo;
        ob[(size_t)o * N_P + lane] = fbuf[lane][o];
    }
}

extern "C" void kernel_launch(void* const* d_in, const int* in_sizes, int n_in,
                              void* d_out, int out_size, void* d_ws, size_t ws_size,
                              hipStream_t stream) {
    (void)in_sizes; (void)n_in; (void)out_size; (void)d_ws; (void)ws_size;
    const float* feat = (const float*)d_in[0];
    const unsigned char* mask = (const unsigned char*)d_in[1];
    const float* W0 = (const float*)d_in[2];
    const float* W1 = (const float*)d_in[3];
    const float* W2 = (const float*)d_in[4];
    const float* Ws = (const float*)d_in[5];
    const float* g0 = (const float*)d_in[6];
    const float* b0 = (const float*)d_in[7];
    const float* m0 = (const float*)d_in[8];
    const float* v0 = (const float*)d_in[9];
    const float* g1 = (const float*)d_in[10];
    const float* b1 = (const float*)d_in[11];
    const float* m1 = (const float*)d_in[12];
    const float* v1 = (const float*)d_in[13];
    const float* g2 = (const float*)d_in[14];
    const float* b2 = (const float*)d_in[15];
    const float* m2 = (const float*)d_in[16];
    const float* v2 = (const float*)d_in[17];
    const float* gs = (const float*)d_in[18];
    const float* bs = (const float*)d_in[19];
    const float* ms = (const float*)d_in[20];
    const float* vs = (const float*)d_in[21];
    float* out = (float*)d_out;

    fused_kernel<<<1024, 256, 0, stream>>>(feat, mask, W0, W1, W2, Ws,
                                           g0, b0, m0, v0, g1, b1, m1, v1,
                                           g2, b2, m2, v2, gs, bs, ms, vs,
                                           out);
}

// Round 8
// 305.022 us; speedup vs baseline: 1.0096x; 1.0096x over previous
//
#include <hip/hip_runtime.h>

#define N_P 1024
#define N_K 16
#define C_IN 18

typedef _Float16 f16;
typedef f16 f16x8 __attribute__((ext_vector_type(8)));
typedef f16 f16x4 __attribute__((ext_vector_type(4)));
typedef float f32x4 __attribute__((ext_vector_type(4)));

// ---------------------------------------------------------------------------
// Fused EdgeConv. Round-8: spill-free shfl merge (sender-preserving).
//  - thread: query qid = lane&15, segment s = lane>>4; f64-key cascade scan
//    (key = (mono(d)<<10)|idx exact in f64; order == reference (d,idx) lex).
//  - merge: 2 shfl_xor rounds (32,16). Send-side lanes insert +INF (no-op,
//    keeps their kk[] bit-unchanged) so receivers can stream the partner's
//    original keys one at a time -- NO tmp[17] snapshot, no VGPR spill
//    (round-7 lesson: tmp[17] spilled kk to scratch: VGPR 64, +80MB HBM).
//  - MLP phase unchanged (verified absmax 0.0625 since round 3).
// LDS: spts[1024]f4 (16384) aliased by fbuf[64][65] (16640), hb 9216,
//      idx_lds 4096 -> 29968 B total.
// ---------------------------------------------------------------------------
__global__ __launch_bounds__(256, 4) void fused_kernel(
    const float* __restrict__ feat, const unsigned char* __restrict__ mask,
    const float* __restrict__ W0, const float* __restrict__ W1,
    const float* __restrict__ W2, const float* __restrict__ Ws,
    const float* __restrict__ g0, const float* __restrict__ b0,
    const float* __restrict__ m0, const float* __restrict__ v0,
    const float* __restrict__ g1, const float* __restrict__ b1,
    const float* __restrict__ m1, const float* __restrict__ v1,
    const float* __restrict__ g2, const float* __restrict__ b2,
    const float* __restrict__ m2, const float* __restrict__ v2,
    const float* __restrict__ gs, const float* __restrict__ bs,
    const float* __restrict__ ms, const float* __restrict__ vs,
    float* __restrict__ out) {

    __shared__ __align__(16) char sbytes[16640 + 9216 + 4096 + 16];
    float4* spts = (float4*)sbytes;                          // [1024]
    float (*fbuf)[65] = (float(*)[65])sbytes;                // aliases spts
    f16 (*hb)[16][72] = (f16(*)[16][72])(sbytes + 16640);    // [4][16][72]
    int (*idx_lds)[16] = (int(*)[16])(sbytes + 16640 + 9216);// [64][16]
    int* msum = (int*)(sbytes + 16640 + 9216 + 4096);

    const int tid = threadIdx.x;
    const int lane = tid & 63;
    const int w = tid >> 6;
    const int g = lane >> 4;
    const int c15 = lane & 15;
    const int n = blockIdx.x >> 4;
    const int P0 = (blockIdx.x & 15) << 6;   // this block's 64 points
    const int PB = P0 + (w << 4);            // this wave's 16 points

    const float* fB = feat + (size_t)n * N_P * C_IN;

    // ---- phase A: stage (x, y, r); count mask ----
    if (tid == 0) *msum = 0;
    __syncthreads();
    for (int i = tid; i < N_P; i += 256) {
        float x = fB[i * C_IN + 0];
        float y = fB[i * C_IN + 1];
        float r = __fadd_rn(__fmul_rn(x, x), __fmul_rn(y, y));
        spts[i] = make_float4(x, y, r, 0.f);
    }
    {
        unsigned int m4 = *(const unsigned int*)(mask + (size_t)n * N_P + tid * 4);
        int mc = (int)(((m4 & 0xFFu) != 0) + (((m4 >> 8) & 0xFFu) != 0) +
                       (((m4 >> 16) & 0xFFu) != 0) + (((m4 >> 24) & 0xFFu) != 0));
        atomicAdd(msum, mc);
    }
    __syncthreads();
    const int valid = N_P - *msum;

    // ---- phase B: segmented scan + spill-free in-wave shfl merge ----
    double kk[17];
    {
        const int qid = c15;                 // wave-local query 0..15
        const int s = g;                     // segment 0..3
        const int base = s << 8;
        const float4 me = spts[P0 + (w << 4) + qid];
        const float px = me.x, py = me.y, rp = me.z;

#pragma unroll
        for (int j = 0; j < 17; ++j) kk[j] = 0x1.0p60;

        int off = (2 * s) & 255;             // bank-skewed start
        float4 nq = spts[base + off];
        for (int i = 0; i < 256; ++i) {
            const float4 qc = nq;
            const int cur = base + off;
            off = (off + 1) & 255;
            nq = spts[base + off];           // broadcast prefetch
            float dot = __fadd_rn(__fmul_rn(px, qc.x), __fmul_rn(py, qc.y));
            float d   = __fadd_rn(__builtin_fmaf(-2.f, dot, rp), qc.z);
            unsigned int ud = __float_as_uint(d);
            ud ^= (unsigned int)((int)ud >> 31) | 0x80000000u;   // monotone map
            double x = __builtin_fma((double)ud, 1024.0, (double)cur); // exact
            // branchless sorted-ascending cascade
#pragma unroll
            for (int j = 0; j < 17; ++j) {
                double lo = fmin(kk[j], x);
                x = fmax(kk[j], x);
                kk[j] = lo;
            }
        }
        // tree merge: xor 32 then 16. Senders insert +INF (exact no-op) so
        // their kk[] stays unmodified while receivers stream original keys.
#pragma unroll
        for (int r = 0; r < 2; ++r) {
            const int m = (r == 0) ? 32 : 16;
            const bool recv = (lane & m) == 0;
#pragma unroll
            for (int j = 0; j < 17; ++j) {
                double x = __shfl_xor(kk[j], m, 64);
                x = recv ? x : __builtin_inf();
#pragma unroll
                for (int jj = 0; jj < 17; ++jj) {
                    double lo = fmin(kk[jj], x);
                    x = fmax(kk[jj], x);
                    kk[jj] = lo;
                }
            }
        }
        if (lane < 16) {
            const int row = (w << 4) + qid;
            // kk[0] = lex-min (d,idx) = self, dropped; kk[1..16] = neighbors
#pragma unroll
            for (int j = 1; j < 17; ++j) {
                double hi = __builtin_trunc(kk[j] * 0x1.0p-10);
                idx_lds[row][j - 1] = (int)(kk[j] - hi * 1024.0);
            }
        }
    }
    __syncthreads();   // all scans done; spts dead -> fbuf writable

    // ---- fold BN into weight fragments (per-lane registers) ----
    float tb0[4], tb1[4], tb2[4], tbs[4];
    f16x8 w0f[4], w1f[4][2], w2f[4][2];
    f16x4 wsf[4];
#pragma unroll
    for (int t = 0; t < 4; ++t) {
        const int o = t * 16 + c15;
        float s0 = g0[o] / sqrtf(v0[o] + 1e-5f);  tb0[t] = b0[o] - m0[o] * s0;
        float s1 = g1[o] / sqrtf(v1[o] + 1e-5f);  tb1[t] = b1[o] - m1[o] * s1;
        float s2 = g2[o] / sqrtf(v2[o] + 1e-5f);  tb2[t] = b2[o] - m2[o] * s2;
        float ss = gs[o] / sqrtf(vs[o] + 1e-5f);  tbs[t] = bs[o] - ms[o] * ss;
        const float* w0r = W0 + o * 32 + g * 8;
#pragma unroll
        for (int e = 0; e < 8; ++e) w0f[t][e] = (f16)(w0r[e] * s0);
        const float* w1r = W1 + o * 64 + g * 8;
        const float* w2r = W2 + o * 64 + g * 8;
#pragma unroll
        for (int ch = 0; ch < 2; ++ch)
#pragma unroll
            for (int e = 0; e < 8; ++e) {
                w1f[t][ch][e] = (f16)(w1r[ch * 32 + e] * s1);
                w2f[t][ch][e] = (f16)(w2r[ch * 32 + e] * s2);
            }
        const float* wsr = Ws + o * 16 + g * 4;
#pragma unroll
        for (int e = 0; e < 4; ++e) wsf[t][e] = (f16)(wsr[e] * ss);
    }

    // ---- per-point MLP: rows = 16 neighbors, cols = 64 channels ----
    for (int pp = 0; pp < 16; ++pp) {
        const int p = PB + pp;
        const int* ip = idx_lds[(w << 4) + pp];

        const int q = ip[c15];
        const int half = g & 1;
        const float* fcp = fB + p * C_IN + 2 + half * 8;
        float e0[8];
#pragma unroll
        for (int j = 0; j < 4; ++j) {
            float2 v = *(const float2*)(fcp + 2 * j);
            e0[2 * j] = v.x; e0[2 * j + 1] = v.y;
        }
        if (g >= 2) {
            const float* fqp = fB + q * C_IN + 2 + half * 8;
#pragma unroll
            for (int j = 0; j < 4; ++j) {
                float2 v = *(const float2*)(fqp + 2 * j);
                e0[2 * j] -= v.x; e0[2 * j + 1] -= v.y;
            }
        }
        f16x8 a0;
#pragma unroll
        for (int j = 0; j < 8; ++j) a0[j] = (f16)e0[j];

        // layer 0 (K=32), folded-BN bias in acc init
        f32x4 acc[4];
#pragma unroll
        for (int t = 0; t < 4; ++t) {
            acc[t] = (f32x4){tb0[t], tb0[t], tb0[t], tb0[t]};
            acc[t] = __builtin_amdgcn_mfma_f32_16x16x32_f16(a0, w0f[t], acc[t], 0, 0, 0);
        }
#pragma unroll
        for (int t = 0; t < 4; ++t)
#pragma unroll
            for (int r = 0; r < 4; ++r)
                hb[w][4 * g + r][t * 16 + c15] = (f16)fmaxf(acc[t][r], 0.f);

        // layer 1 (K=64)
        f16x8 a1a = *(const f16x8*)&hb[w][c15][g * 8];
        f16x8 a1b = *(const f16x8*)&hb[w][c15][32 + g * 8];
        f32x4 acc1[4];
#pragma unroll
        for (int t = 0; t < 4; ++t) {
            acc1[t] = (f32x4){tb1[t], tb1[t], tb1[t], tb1[t]};
            acc1[t] = __builtin_amdgcn_mfma_f32_16x16x32_f16(a1a, w1f[t][0], acc1[t], 0, 0, 0);
            acc1[t] = __builtin_amdgcn_mfma_f32_16x16x32_f16(a1b, w1f[t][1], acc1[t], 0, 0, 0);
        }
#pragma unroll
        for (int t = 0; t < 4; ++t)
#pragma unroll
            for (int r = 0; r < 4; ++r)
                hb[w][4 * g + r][t * 16 + c15] = (f16)fmaxf(acc1[t][r], 0.f);

        // layer 2 (K=64) + neighbor mask + k-mean
        f16x8 a2a = *(const f16x8*)&hb[w][c15][g * 8];
        f16x8 a2b = *(const f16x8*)&hb[w][c15][32 + g * 8];
        f32x4 acc2[4];
#pragma unroll
        for (int t = 0; t < 4; ++t) {
            acc2[t] = (f32x4){tb2[t], tb2[t], tb2[t], tb2[t]};
            acc2[t] = __builtin_amdgcn_mfma_f32_16x16x32_f16(a2a, w2f[t][0], acc2[t], 0, 0, 0);
            acc2[t] = __builtin_amdgcn_mfma_f32_16x16x32_f16(a2b, w2f[t][1], acc2[t], 0, 0, 0);
        }
        float ssum[4] = {0.f, 0.f, 0.f, 0.f};
        int cnt = 0;
#pragma unroll
        for (int r = 0; r < 4; ++r) {
            int qq = ip[4 * g + r];
            bool fl = (qq >= valid);
            cnt += fl ? 1 : 0;
#pragma unroll
            for (int t = 0; t < 4; ++t) {
                float v = fmaxf(acc2[t][r], 0.f);
                ssum[t] += fl ? 0.f : v;
            }
        }
#pragma unroll
        for (int t = 0; t < 4; ++t) {
            ssum[t] += __shfl_xor(ssum[t], 16);
            ssum[t] += __shfl_xor(ssum[t], 32);
        }
        cnt += __shfl_xor(cnt, 16);
        cnt += __shfl_xor(cnt, 32);
        float dn = fmaxf((float)(N_K - cnt), 1e-8f);
        if (g == 0) {
            int prow = (w << 4) + pp;
#pragma unroll
            for (int t = 0; t < 4; ++t)
                fbuf[prow][t * 16 + c15] = ssum[t] / dn;
        }
    }

    // ---- shortcut: sc = BN(Ws @ X) via 16x16x16 MFMA, rows = wave's 16 p ----
    {
        const float* xr = fB + (size_t)(PB + c15) * C_IN + 2 + g * 4;
        float2 xa = *(const float2*)(xr);
        float2 xb = *(const float2*)(xr + 2);
        f16x4 as;
        as[0] = (f16)xa.x; as[1] = (f16)xa.y; as[2] = (f16)xb.x; as[3] = (f16)xb.y;
        f32x4 sacc[4];
#pragma unroll
        for (int t = 0; t < 4; ++t) {
            sacc[t] = (f32x4){tbs[t], tbs[t], tbs[t], tbs[t]};
            sacc[t] = __builtin_amdgcn_mfma_f32_16x16x16f16(as, wsf[t], sacc[t], 0, 0, 0);
        }
        const unsigned char* mrow = mask + (size_t)n * N_P + P0;
#pragma unroll
        for (int r = 0; r < 4; ++r) {
            int pl = (w << 4) + 4 * g + r;
            bool mk = (mrow[pl] != 0);
#pragma unroll
            for (int t = 0; t < 4; ++t) {
                float a = fbuf[pl][t * 16 + c15];
                float sv = mk ? 0.f : sacc[t][r];
                fbuf[pl][t * 16 + c15] = fmaxf(a + sv, 0.f);
            }
        }
    }
    __syncthreads();

    // ---- transposed store: out[n][o][p], coalesced 256B per wave ----
    float* ob = out + (size_t)n * 64 * N_P + P0;
#pragma unroll
    for (int oo = 0; oo < 16; ++oo) {
        int o = (w << 4) + oo;
        ob[(size_t)o * N_P + lane] = fbuf[lane][o];
    }
}

extern "C" void kernel_launch(void* const* d_in, const int* in_sizes, int n_in,
                              void* d_out, int out_size, void* d_ws, size_t ws_size,
                              hipStream_t stream) {
    (void)in_sizes; (void)n_in; (void)out_size; (void)d_ws; (void)ws_size;
    const float* feat = (const float*)d_in[0];
    const unsigned char* mask = (const unsigned char*)d_in[1];
    const float* W0 = (const float*)d_in[2];
    const float* W1 = (const float*)d_in[3];
    const float* W2 = (const float*)d_in[4];
    const float* Ws = (const float*)d_in[5];
    const float* g0 = (const float*)d_in[6];
    const float* b0 = (const float*)d_in[7];
    const float* m0 = (const float*)d_in[8];
    const float* v0 = (const float*)d_in[9];
    const float* g1 = (const float*)d_in[10];
    const float* b1 = (const float*)d_in[11];
    const float* m1 = (const float*)d_in[12];
    const float* v1 = (const float*)d_in[13];
    const float* g2 = (const float*)d_in[14];
    const float* b2 = (const float*)d_in[15];
    const float* m2 = (const float*)d_in[16];
    const float* v2 = (const float*)d_in[17];
    const float* gs = (const float*)d_in[18];
    const float* bs = (const float*)d_in[19];
    const float* ms = (const float*)d_in[20];
    const float* vs = (const float*)d_in[21];
    float* out = (float*)d_out;

    fused_kernel<<<1024, 256, 0, stream>>>(feat, mask, W0, W1, W2, Ws,
                                           g0, b0, m0, v0, g1, b1, m1, v1,
                                           g2, b2, m2, v2, gs, bs, ms, vs,
                                           out);
}

// Round 9
// 295.138 us; speedup vs baseline: 1.0434x; 1.0335x over previous
//
#include <hip/hip_runtime.h>

#define N_P 1024
#define N_K 16
#define C_IN 18

typedef _Float16 f16;
typedef f16 f16x8 __attribute__((ext_vector_type(8)));
typedef f16 f16x4 __attribute__((ext_vector_type(4)));
typedef float f32x4 __attribute__((ext_vector_type(4)));

// ---------------------------------------------------------------------------
// Fused EdgeConv. Round-9: round-8 structure with __launch_bounds__(256,3).
// Round-8 lesson: the (256,4) hint clamped VGPR to 64 (8-wave budget), which
// spilled kk[17] (34 VGPRs of f64 keys) to scratch inside the 256-iter scan
// loop: +40MB FETCH and +40MB WRITE. (256,3) allows ~170 VGPR; round-6 code
// compiled to 84 VGPR spill-free under it.
//  - scan: thread = (query lane&15, segment lane>>4); f64-key cascade
//    (key = (mono(d)<<10)|idx exact in f64; order == reference (d,idx) lex).
//  - merge: 2 shfl_xor rounds (32,16); senders insert +INF (exact no-op) so
//    kk[] stays unmodified while receivers stream the partner's keys.
//  - MLP phase unchanged (verified absmax 0.0625 since round 3).
// LDS: spts[1024]f4 (16384) aliased by fbuf[64][65] (16640), hb 9216,
//      idx_lds 4096 -> 29968 B total => 4-5 blocks/CU by LDS.
// ---------------------------------------------------------------------------
__global__ __launch_bounds__(256, 3) void fused_kernel(
    const float* __restrict__ feat, const unsigned char* __restrict__ mask,
    const float* __restrict__ W0, const float* __restrict__ W1,
    const float* __restrict__ W2, const float* __restrict__ Ws,
    const float* __restrict__ g0, const float* __restrict__ b0,
    const float* __restrict__ m0, const float* __restrict__ v0,
    const float* __restrict__ g1, const float* __restrict__ b1,
    const float* __restrict__ m1, const float* __restrict__ v1,
    const float* __restrict__ g2, const float* __restrict__ b2,
    const float* __restrict__ m2, const float* __restrict__ v2,
    const float* __restrict__ gs, const float* __restrict__ bs,
    const float* __restrict__ ms, const float* __restrict__ vs,
    float* __restrict__ out) {

    __shared__ __align__(16) char sbytes[16640 + 9216 + 4096 + 16];
    float4* spts = (float4*)sbytes;                          // [1024]
    float (*fbuf)[65] = (float(*)[65])sbytes;                // aliases spts
    f16 (*hb)[16][72] = (f16(*)[16][72])(sbytes + 16640);    // [4][16][72]
    int (*idx_lds)[16] = (int(*)[16])(sbytes + 16640 + 9216);// [64][16]
    int* msum = (int*)(sbytes + 16640 + 9216 + 4096);

    const int tid = threadIdx.x;
    const int lane = tid & 63;
    const int w = tid >> 6;
    const int g = lane >> 4;
    const int c15 = lane & 15;
    const int n = blockIdx.x >> 4;
    const int P0 = (blockIdx.x & 15) << 6;   // this block's 64 points
    const int PB = P0 + (w << 4);            // this wave's 16 points

    const float* fB = feat + (size_t)n * N_P * C_IN;

    // ---- phase A: stage (x, y, r); count mask ----
    if (tid == 0) *msum = 0;
    __syncthreads();
    for (int i = tid; i < N_P; i += 256) {
        float x = fB[i * C_IN + 0];
        float y = fB[i * C_IN + 1];
        float r = __fadd_rn(__fmul_rn(x, x), __fmul_rn(y, y));
        spts[i] = make_float4(x, y, r, 0.f);
    }
    {
        unsigned int m4 = *(const unsigned int*)(mask + (size_t)n * N_P + tid * 4);
        int mc = (int)(((m4 & 0xFFu) != 0) + (((m4 >> 8) & 0xFFu) != 0) +
                       (((m4 >> 16) & 0xFFu) != 0) + (((m4 >> 24) & 0xFFu) != 0));
        atomicAdd(msum, mc);
    }
    __syncthreads();
    const int valid = N_P - *msum;

    // ---- phase B: segmented scan + spill-free in-wave shfl merge ----
    double kk[17];
    {
        const int qid = c15;                 // wave-local query 0..15
        const int s = g;                     // segment 0..3
        const int base = s << 8;
        const float4 me = spts[P0 + (w << 4) + qid];
        const float px = me.x, py = me.y, rp = me.z;

#pragma unroll
        for (int j = 0; j < 17; ++j) kk[j] = 0x1.0p60;

        int off = (2 * s) & 255;             // bank-skewed start
        float4 nq = spts[base + off];
        for (int i = 0; i < 256; ++i) {
            const float4 qc = nq;
            const int cur = base + off;
            off = (off + 1) & 255;
            nq = spts[base + off];           // broadcast prefetch
            float dot = __fadd_rn(__fmul_rn(px, qc.x), __fmul_rn(py, qc.y));
            float d   = __fadd_rn(__builtin_fmaf(-2.f, dot, rp), qc.z);
            unsigned int ud = __float_as_uint(d);
            ud ^= (unsigned int)((int)ud >> 31) | 0x80000000u;   // monotone map
            double x = __builtin_fma((double)ud, 1024.0, (double)cur); // exact
            // branchless sorted-ascending cascade
#pragma unroll
            for (int j = 0; j < 17; ++j) {
                double lo = fmin(kk[j], x);
                x = fmax(kk[j], x);
                kk[j] = lo;
            }
        }
        // tree merge: xor 32 then 16. Senders insert +INF (exact no-op) so
        // their kk[] stays unmodified while receivers stream original keys.
#pragma unroll
        for (int r = 0; r < 2; ++r) {
            const int m = (r == 0) ? 32 : 16;
            const bool recv = (lane & m) == 0;
#pragma unroll
            for (int j = 0; j < 17; ++j) {
                double x = __shfl_xor(kk[j], m, 64);
                x = recv ? x : __builtin_inf();
#pragma unroll
                for (int jj = 0; jj < 17; ++jj) {
                    double lo = fmin(kk[jj], x);
                    x = fmax(kk[jj], x);
                    kk[jj] = lo;
                }
            }
        }
        if (lane < 16) {
            const int row = (w << 4) + qid;
            // kk[0] = lex-min (d,idx) = self, dropped; kk[1..16] = neighbors
#pragma unroll
            for (int j = 1; j < 17; ++j) {
                double hi = __builtin_trunc(kk[j] * 0x1.0p-10);
                idx_lds[row][j - 1] = (int)(kk[j] - hi * 1024.0);
            }
        }
    }
    __syncthreads();   // all scans done; spts dead -> fbuf writable

    // ---- fold BN into weight fragments (per-lane registers) ----
    float tb0[4], tb1[4], tb2[4], tbs[4];
    f16x8 w0f[4], w1f[4][2], w2f[4][2];
    f16x4 wsf[4];
#pragma unroll
    for (int t = 0; t < 4; ++t) {
        const int o = t * 16 + c15;
        float s0 = g0[o] / sqrtf(v0[o] + 1e-5f);  tb0[t] = b0[o] - m0[o] * s0;
        float s1 = g1[o] / sqrtf(v1[o] + 1e-5f);  tb1[t] = b1[o] - m1[o] * s1;
        float s2 = g2[o] / sqrtf(v2[o] + 1e-5f);  tb2[t] = b2[o] - m2[o] * s2;
        float ss = gs[o] / sqrtf(vs[o] + 1e-5f);  tbs[t] = bs[o] - ms[o] * ss;
        const float* w0r = W0 + o * 32 + g * 8;
#pragma unroll
        for (int e = 0; e < 8; ++e) w0f[t][e] = (f16)(w0r[e] * s0);
        const float* w1r = W1 + o * 64 + g * 8;
        const float* w2r = W2 + o * 64 + g * 8;
#pragma unroll
        for (int ch = 0; ch < 2; ++ch)
#pragma unroll
            for (int e = 0; e < 8; ++e) {
                w1f[t][ch][e] = (f16)(w1r[ch * 32 + e] * s1);
                w2f[t][ch][e] = (f16)(w2r[ch * 32 + e] * s2);
            }
        const float* wsr = Ws + o * 16 + g * 4;
#pragma unroll
        for (int e = 0; e < 4; ++e) wsf[t][e] = (f16)(wsr[e] * ss);
    }

    // ---- per-point MLP: rows = 16 neighbors, cols = 64 channels ----
    for (int pp = 0; pp < 16; ++pp) {
        const int p = PB + pp;
        const int* ip = idx_lds[(w << 4) + pp];

        const int q = ip[c15];
        const int half = g & 1;
        const float* fcp = fB + p * C_IN + 2 + half * 8;
        float e0[8];
#pragma unroll
        for (int j = 0; j < 4; ++j) {
            float2 v = *(const float2*)(fcp + 2 * j);
            e0[2 * j] = v.x; e0[2 * j + 1] = v.y;
        }
        if (g >= 2) {
            const float* fqp = fB + q * C_IN + 2 + half * 8;
#pragma unroll
            for (int j = 0; j < 4; ++j) {
                float2 v = *(const float2*)(fqp + 2 * j);
                e0[2 * j] -= v.x; e0[2 * j + 1] -= v.y;
            }
        }
        f16x8 a0;
#pragma unroll
        for (int j = 0; j < 8; ++j) a0[j] = (f16)e0[j];

        // layer 0 (K=32), folded-BN bias in acc init
        f32x4 acc[4];
#pragma unroll
        for (int t = 0; t < 4; ++t) {
            acc[t] = (f32x4){tb0[t], tb0[t], tb0[t], tb0[t]};
            acc[t] = __builtin_amdgcn_mfma_f32_16x16x32_f16(a0, w0f[t], acc[t], 0, 0, 0);
        }
#pragma unroll
        for (int t = 0; t < 4; ++t)
#pragma unroll
            for (int r = 0; r < 4; ++r)
                hb[w][4 * g + r][t * 16 + c15] = (f16)fmaxf(acc[t][r], 0.f);

        // layer 1 (K=64)
        f16x8 a1a = *(const f16x8*)&hb[w][c15][g * 8];
        f16x8 a1b = *(const f16x8*)&hb[w][c15][32 + g * 8];
        f32x4 acc1[4];
#pragma unroll
        for (int t = 0; t < 4; ++t) {
            acc1[t] = (f32x4){tb1[t], tb1[t], tb1[t], tb1[t]};
            acc1[t] = __builtin_amdgcn_mfma_f32_16x16x32_f16(a1a, w1f[t][0], acc1[t], 0, 0, 0);
            acc1[t] = __builtin_amdgcn_mfma_f32_16x16x32_f16(a1b, w1f[t][1], acc1[t], 0, 0, 0);
        }
#pragma unroll
        for (int t = 0; t < 4; ++t)
#pragma unroll
            for (int r = 0; r < 4; ++r)
                hb[w][4 * g + r][t * 16 + c15] = (f16)fmaxf(acc1[t][r], 0.f);

        // layer 2 (K=64) + neighbor mask + k-mean
        f16x8 a2a = *(const f16x8*)&hb[w][c15][g * 8];
        f16x8 a2b = *(const f16x8*)&hb[w][c15][32 + g * 8];
        f32x4 acc2[4];
#pragma unroll
        for (int t = 0; t < 4; ++t) {
            acc2[t] = (f32x4){tb2[t], tb2[t], tb2[t], tb2[t]};
            acc2[t] = __builtin_amdgcn_mfma_f32_16x16x32_f16(a2a, w2f[t][0], acc2[t], 0, 0, 0);
            acc2[t] = __builtin_amdgcn_mfma_f32_16x16x32_f16(a2b, w2f[t][1], acc2[t], 0, 0, 0);
        }
        float ssum[4] = {0.f, 0.f, 0.f, 0.f};
        int cnt = 0;
#pragma unroll
        for (int r = 0; r < 4; ++r) {
            int qq = ip[4 * g + r];
            bool fl = (qq >= valid);
            cnt += fl ? 1 : 0;
#pragma unroll
            for (int t = 0; t < 4; ++t) {
                float v = fmaxf(acc2[t][r], 0.f);
                ssum[t] += fl ? 0.f : v;
            }
        }
#pragma unroll
        for (int t = 0; t < 4; ++t) {
            ssum[t] += __shfl_xor(ssum[t], 16);
            ssum[t] += __shfl_xor(ssum[t], 32);
        }
        cnt += __shfl_xor(cnt, 16);
        cnt += __shfl_xor(cnt, 32);
        float dn = fmaxf((float)(N_K - cnt), 1e-8f);
        if (g == 0) {
            int prow = (w << 4) + pp;
#pragma unroll
            for (int t = 0; t < 4; ++t)
                fbuf[prow][t * 16 + c15] = ssum[t] / dn;
        }
    }

    // ---- shortcut: sc = BN(Ws @ X) via 16x16x16 MFMA, rows = wave's 16 p ----
    {
        const float* xr = fB + (size_t)(PB + c15) * C_IN + 2 + g * 4;
        float2 xa = *(const float2*)(xr);
        float2 xb = *(const float2*)(xr + 2);
        f16x4 as;
        as[0] = (f16)xa.x; as[1] = (f16)xa.y; as[2] = (f16)xb.x; as[3] = (f16)xb.y;
        f32x4 sacc[4];
#pragma unroll
        for (int t = 0; t < 4; ++t) {
            sacc[t] = (f32x4){tbs[t], tbs[t], tbs[t], tbs[t]};
            sacc[t] = __builtin_amdgcn_mfma_f32_16x16x16f16(as, wsf[t], sacc[t], 0, 0, 0);
        }
        const unsigned char* mrow = mask + (size_t)n * N_P + P0;
#pragma unroll
        for (int r = 0; r < 4; ++r) {
            int pl = (w << 4) + 4 * g + r;
            bool mk = (mrow[pl] != 0);
#pragma unroll
            for (int t = 0; t < 4; ++t) {
                float a = fbuf[pl][t * 16 + c15];
                float sv = mk ? 0.f : sacc[t][r];
                fbuf[pl][t * 16 + c15] = fmaxf(a + sv, 0.f);
            }
        }
    }
    __syncthreads();

    // ---- transposed store: out[n][o][p], coalesced 256B per wave ----
    float* ob = out + (size_t)n * 64 * N_P + P0;
#pragma unroll
    for (int oo = 0; oo < 16; ++oo) {
        int o = (w << 4) + oo;
        ob[(size_t)o * N_P + lane] = fbuf[lane][o];
    }
}

extern "C" void kernel_launch(void* const* d_in, const int* in_sizes, int n_in,
                              void* d_out, int out_size, void* d_ws, size_t ws_size,
                              hipStream_t stream) {
    (void)in_sizes; (void)n_in; (void)out_size; (void)d_ws; (void)ws_size;
    const float* feat = (const float*)d_in[0];
    const unsigned char* mask = (const unsigned char*)d_in[1];
    const float* W0 = (const float*)d_in[2];
    const float* W1 = (const float*)d_in[3];
    const float* W2 = (const float*)d_in[4];
    const float* Ws = (const float*)d_in[5];
    const float* g0 = (const float*)d_in[6];
    const float* b0 = (const float*)d_in[7];
    const float* m0 = (const float*)d_in[8];
    const float* v0 = (const float*)d_in[9];
    const float* g1 = (const float*)d_in[10];
    const float* b1 = (const float*)d_in[11];
    const float* m1 = (const float*)d_in[12];
    const float* v1 = (const float*)d_in[13];
    const float* g2 = (const float*)d_in[14];
    const float* b2 = (const float*)d_in[15];
    const float* m2 = (const float*)d_in[16];
    const float* v2 = (const float*)d_in[17];
    const float* gs = (const float*)d_in[18];
    const float* bs = (const float*)d_in[19];
    const float* ms = (const float*)d_in[20];
    const float* vs = (const float*)d_in[21];
    float* out = (float*)d_out;

    fused_kernel<<<1024, 256, 0, stream>>>(feat, mask, W0, W1, W2, Ws,
                                           g0, b0, m0, v0, g1, b1, m1, v1,
                                           g2, b2, m2, v2, gs, bs, ms, vs,
                                           out);
}